// Round 9
// baseline (420.077 us; speedup 1.0000x reference)
//
#include <hip/hip_runtime.h>

// Spin-weighted spherical convolution, R=64, L=32, M=63, S=2, C=64, B=32.
// Stages: DFT(phi) -> Legendre fwd -> channel mix (in-place) -> Legendre bwd
// -> IDFT(phi). All fp32 (no fp32 MFMA on CDNA4).
// R3: k_leg_bwd spill fix (2968 -> 678 us, confirmed).
// R6: radix-8x8 DFT/IDFT (678 -> 407 us, confirmed).
// R7: k_mix was latency-bound (VALU 56%, 31% FMA eff) on serial per-ic
// global k loads. Software-pipeline: prefetch ic+1's kr/ki during ic's
// 64-FMA body; hoist k base pointers.
// R8: resubmit (infra failure, R7 kernel never ran).

#define TWO_PI_F 6.283185307179586f

// g layout: [mi(63)][s(2)][j(64)][b(32)][c(64)]  -> 16,515,072 floats per re/im
// a layout: [l(32)][mi(63)][b(32)][ic(128)]      -> 8,257,536 floats per re/im
// h layout: [b(32)][j(64)][mi(63)][sd(128)]      -> 16,515,072 floats per re/im

// Radix-8x8 forward DFT. Block = (b, j, s, ch): 32 channels x 8 k8-groups.
__global__ __launch_bounds__(256) void k_dft_fwd(
    const float* __restrict__ fre, const float* __restrict__ fim,
    const float* __restrict__ qw, float* __restrict__ gre, float* __restrict__ gim)
{
  __shared__ float sre[64][32];
  __shared__ float sim2[64][32];
  __shared__ float Are[64][32];
  __shared__ float Aim[64][32];
  __shared__ float2 tw[64];
  const int bid = blockIdx.x;          // (((b*64 + j)*2 + s)*2 + ch)
  const int ch = bid & 1;
  const int s = (bid >> 1) & 1;
  const int j = (bid >> 2) & 63;
  const int b = bid >> 8;
  const int t = threadIdx.x;
  if (t < 64) {
    float ang = (TWO_PI_F / 64.0f) * (float)t;
    tw[t] = make_float2(cosf(ang), sinf(ang));
  }
  const int coff = s * 64 + ch * 32;
  const size_t base = ((size_t)(b * 64 + j) * 64) * 128 + coff;
  for (int v = t; v < 512; v += 256) {
    const int p = v >> 3;
    const int q4 = (v & 7) * 4;
    *(float4*)(&sre[p][q4])  = *(const float4*)(fre + base + (size_t)p * 128 + q4);
    *(float4*)(&sim2[p][q4]) = *(const float4*)(fim + base + (size_t)p * 128 + q4);
  }
  __syncthreads();
  const int c = t & 31;
  const int g = t >> 5;                // k8 in phase1; k = g + 8*ii in phase2
  float t8x[8], t8y[8];                // W8^{-g p2} = conj(tw[8 g p2])
#pragma unroll
  for (int p2 = 0; p2 < 8; ++p2) {
    const float2 w = tw[(8 * g * p2) & 63];
    t8x[p2] = w.x; t8y[p2] = w.y;
  }
#pragma unroll
  for (int p1 = 0; p1 < 8; ++p1) {
    float accr = 0.f, acci = 0.f;
#pragma unroll
    for (int p2 = 0; p2 < 8; ++p2) {
      const float fr = sre[p1 + 8 * p2][c];
      const float fi = sim2[p1 + 8 * p2][c];
      accr += fr * t8x[p2] + fi * t8y[p2];
      acci += fi * t8x[p2] - fr * t8y[p2];
    }
    Are[p1 * 8 + g][c] = accr;
    Aim[p1 * 8 + g][c] = acci;
  }
  __syncthreads();
  const float scale = (TWO_PI_F / 64.0f) * qw[j];
  float Ar[8], Ai[8];                  // reg-cache: same A row set for all ii
#pragma unroll
  for (int p1 = 0; p1 < 8; ++p1) {
    Ar[p1] = Are[p1 * 8 + g][c];
    Ai[p1] = Aim[p1 * 8 + g][c];
  }
#pragma unroll
  for (int ii = 0; ii < 8; ++ii) {
    const int k = g + 8 * ii;
    if (k == 32) continue;             // |m|>31 unused (wave-uniform branch)
    float accr = 0.f, acci = 0.f;
#pragma unroll
    for (int p1 = 0; p1 < 8; ++p1) {
      const float2 w = tw[(k * p1) & 63];
      accr += Ar[p1] * w.x + Ai[p1] * w.y;
      acci += Ai[p1] * w.x - Ar[p1] * w.y;
    }
    const int mi = (k < 32) ? (k + 31) : (k - 33);   // m = k or k-64; mi = m+31
    const size_t off = ((size_t)(mi * 2 + s) * 64 + j) * 2048 + b * 64 + ch * 32 + c;
    gre[off] = accr * scale;
    gim[off] = acci * scale;
  }
}

__global__ __launch_bounds__(256) void k_leg_fwd(
    const float* __restrict__ leg, const float* __restrict__ gre,
    const float* __restrict__ gim, float* __restrict__ are, float* __restrict__ aim)
{
  __shared__ float legS[32][64];
  const int bid = blockIdx.x;          // (mi*2 + s)*8 + tile
  const int tile = bid & 7;
  const int s = (bid >> 3) & 1;
  const int mi = bid >> 4;             // 0..62
  const int mval = mi - 31;
  const int am = mval < 0 ? -mval : mval;
  const int nl = 32 - am;
  const int t = threadIdx.x;
  for (int v = t; v < 2048; v += 256) {
    const int l2 = v >> 6, jj = v & 63;
    float val = 0.f;
    if (l2 < nl) {
      const int l = am + l2;
      val = leg[(size_t)((s * 32 + l) * 63 + mi) * 64 + jj];
    }
    legS[l2][jj] = val;
  }
  __syncthreads();
  const int bc = tile * 256 + t;
  const size_t gbase = (size_t)(mi * 2 + s) * 131072 + bc;
  float xr[32], xi[32];
#pragma unroll
  for (int l2 = 0; l2 < 32; ++l2) { xr[l2] = 0.f; xi[l2] = 0.f; }
  for (int j4 = 0; j4 < 16; ++j4) {
    float gr[4], gi[4];
#pragma unroll
    for (int u = 0; u < 4; ++u) {
      gr[u] = gre[gbase + (size_t)(j4 * 4 + u) * 2048];
      gi[u] = gim[gbase + (size_t)(j4 * 4 + u) * 2048];
    }
#pragma unroll
    for (int l2 = 0; l2 < 32; ++l2) {
      const float4 lg = *(const float4*)(&legS[l2][j4 * 4]);
      xr[l2] += lg.x * gr[0] + lg.y * gr[1] + lg.z * gr[2] + lg.w * gr[3];
      xi[l2] += lg.x * gi[0] + lg.y * gi[1] + lg.z * gi[2] + lg.w * gi[3];
    }
  }
  const int b = bc >> 6, c = bc & 63;
#pragma unroll
  for (int l2 = 0; l2 < 32; ++l2) {
    if (l2 < nl) {
      const int l = am + l2;
      const size_t off = ((size_t)(l * 63 + mi) * 32 + b) * 128 + s * 64 + c;
      are[off] = xr[l2];
      aim[off] = xi[l2];
    }
  }
}

// In-place channel/spin mix with software-pipelined k loads (R7).
__global__ __launch_bounds__(256) void k_mix(
    float* __restrict__ are, float* __restrict__ aim,
    const float* __restrict__ kre, const float* __restrict__ kim)
{
  __shared__ float sar[32][132];   // +4 pad: kills same-bank conflict on column reads
  __shared__ float sai[32][132];
  const int q = blockIdx.x;        // 1024 valid (l,mi): q = l^2 + (mi - (31-l))
  int l = (int)floorf(sqrtf((float)q));
  if ((l + 1) * (l + 1) <= q) ++l;
  if (l * l > q) --l;
  const int mi = 31 - l + (q - l * l);
  const int t = threadIdx.x;
  const size_t abase = (size_t)(l * 63 + mi) * 4096;
  for (int v = t; v < 1024; v += 256) {
    const int bb = v >> 5;
    const int c4 = (v & 31) * 4;
    *(float4*)(&sar[bb][c4]) = *(const float4*)(are + abase + v * 4);
    *(float4*)(&sai[bb][c4]) = *(const float4*)(aim + abase + v * 4);
  }
  __syncthreads();
  const int od0 = (t & 31) * 4;
  const int b0 = (t >> 5) * 4;
  const int o = od0 >> 6;
  const int d0 = od0 & 63;
  // k access for ic = (i*64 + cc): koff = i*8192 + cc*64 floats from kbase
  const float* __restrict__ kr_p = kre + (size_t)l * 16384 + (size_t)o * 4096 + d0;
  const float* __restrict__ ki_p = kim + (size_t)l * 16384 + (size_t)o * 4096 + d0;
  float cr[4][4], ci[4][4];
#pragma unroll
  for (int r = 0; r < 4; ++r)
#pragma unroll
    for (int u = 0; u < 4; ++u) { cr[r][u] = 0.f; ci[r][u] = 0.f; }
  float4 kr = *(const float4*)(kr_p);          // prefetch ic=0
  float4 ki = *(const float4*)(ki_p);
#pragma unroll 2
  for (int ic = 0; ic < 128; ++ic) {
    float4 krn = kr, kin = ki;
    if (ic < 127) {                            // prefetch ic+1 (hides L2 latency
      const int icn = ic + 1;                  //  under this iteration's 64 FMA)
      const size_t koffn = (size_t)(icn >> 6) * 8192 + (size_t)(icn & 63) * 64;
      krn = *(const float4*)(kr_p + koffn);
      kin = *(const float4*)(ki_p + koffn);
    }
    float arv[4], aiv[4];
#pragma unroll
    for (int r = 0; r < 4; ++r) { arv[r] = sar[b0 + r][ic]; aiv[r] = sai[b0 + r][ic]; }
#pragma unroll
    for (int r = 0; r < 4; ++r) {
      cr[r][0] += arv[r] * kr.x - aiv[r] * ki.x; ci[r][0] += arv[r] * ki.x + aiv[r] * kr.x;
      cr[r][1] += arv[r] * kr.y - aiv[r] * ki.y; ci[r][1] += arv[r] * ki.y + aiv[r] * kr.y;
      cr[r][2] += arv[r] * kr.z - aiv[r] * ki.z; ci[r][2] += arv[r] * ki.z + aiv[r] * kr.z;
      cr[r][3] += arv[r] * kr.w - aiv[r] * ki.w; ci[r][3] += arv[r] * ki.w + aiv[r] * kr.w;
    }
    kr = krn; ki = kin;
  }
#pragma unroll
  for (int r = 0; r < 4; ++r) {
    const size_t off = abase + (size_t)(b0 + r) * 128 + od0;
    *(float4*)(are + off) = make_float4(cr[r][0], cr[r][1], cr[r][2], cr[r][3]);
    *(float4*)(aim + off) = make_float4(ci[r][0], ci[r][1], ci[r][2], ci[r][3]);
  }
}

// R3 structure: inverted loop nest, j-accumulators in regs (statically
// indexed), x streamed one elem at a time, re/im passes pinned sequential.
__global__ __launch_bounds__(256) void k_leg_bwd(
    const float* __restrict__ leg, const float* __restrict__ ore,
    const float* __restrict__ oim, float* __restrict__ hre, float* __restrict__ him)
{
  __shared__ float legS[32][64];
  const int bid = blockIdx.x;        // (mi*2 + s)*8 + tile
  const int tile = bid & 7;
  const int s = (bid >> 3) & 1;      // output spin
  const int mi = bid >> 4;
  const int mval = mi - 31;
  const int am = mval < 0 ? -mval : mval;
  const int nl = 32 - am;
  const int t = threadIdx.x;
  for (int v = t; v < 2048; v += 256) {
    const int l2 = v >> 6, jj = v & 63;
    float val = 0.f;
    if (l2 < nl) {
      const int l = am + l2;
      val = leg[(size_t)((s * 32 + l) * 63 + mi) * 64 + jj];
    }
    legS[l2][jj] = val;
  }
  __syncthreads();
  const int bd = tile * 256 + t;
  const int b = bd >> 6, d = bd & 63;
  const size_t lstr = (size_t)63 * 32 * 128;                       // a l-stride
  const size_t abase = ((size_t)(am * 63 + mi) * 32 + b) * 128 + s * 64 + d;
  const size_t hb = (size_t)(b * 64) * 8064 + (size_t)mi * 128 + s * 64 + d;
#pragma unroll 1
  for (int pass = 0; pass < 2; ++pass) {
    const float* __restrict__ src = pass ? oim : ore;
    float* __restrict__ dst = pass ? him : hre;
    float acc[16][4];
#pragma unroll
    for (int j4 = 0; j4 < 16; ++j4)
#pragma unroll
      for (int u = 0; u < 4; ++u) acc[j4][u] = 0.f;
#pragma unroll 1
    for (int l2 = 0; l2 < 32; ++l2) {
      if (l2 >= nl) break;
      const float xv = src[abase + (size_t)l2 * lstr];
#pragma unroll
      for (int j4 = 0; j4 < 16; ++j4) {
        const float4 lg = *(const float4*)(&legS[l2][j4 * 4]);
        acc[j4][0] += lg.x * xv;
        acc[j4][1] += lg.y * xv;
        acc[j4][2] += lg.z * xv;
        acc[j4][3] += lg.w * xv;
      }
    }
#pragma unroll
    for (int j4 = 0; j4 < 16; ++j4) {
      const size_t o0 = hb + (size_t)(j4 * 4) * 8064;
      dst[o0]            = acc[j4][0];
      dst[o0 + 8064]     = acc[j4][1];
      dst[o0 + 2 * 8064] = acc[j4][2];
      dst[o0 + 3 * 8064] = acc[j4][3];
    }
  }
}

// Radix-8x8 inverse DFT. Block = (b, j, s, dh): 32 d-channels x 8 p8-groups.
template <int REAL_ONLY>
__global__ __launch_bounds__(256) void k_idft(
    const float* __restrict__ hre, const float* __restrict__ him,
    float* __restrict__ out)
{
  __shared__ float Hre[64][32];
  __shared__ float Him[64][32];
  __shared__ float Bre[64][32];
  __shared__ float Bim[64][32];
  __shared__ float2 tw[64];
  const int bid = blockIdx.x;        // (((b*64 + j)*2 + s)*2 + dh)
  const int dh = bid & 1;
  const int s = (bid >> 1) & 1;
  const int j = (bid >> 2) & 63;
  const int b = bid >> 8;
  const int t = threadIdx.x;
  if (t < 64) {
    float ang = (TWO_PI_F / 64.0f) * (float)t;
    tw[t] = make_float2(cosf(ang), sinf(ang));
  }
  const size_t hbase = (size_t)(b * 64 + j) * 8064 + s * 64 + dh * 32;
  for (int v = t; v < 512; v += 256) {
    const int k = v >> 3;
    const int q4 = (v & 7) * 4;
    float4 vr = make_float4(0.f, 0.f, 0.f, 0.f), vi = vr;
    if (k != 32) {
      const int mi = (k + 31) & 63;
      vr = *(const float4*)(hre + hbase + (size_t)mi * 128 + q4);
      vi = *(const float4*)(him + hbase + (size_t)mi * 128 + q4);
    }
    *(float4*)(&Hre[k][q4]) = vr;
    *(float4*)(&Him[k][q4]) = vi;
  }
  __syncthreads();
  const int d = t & 31;
  const int g = t >> 5;              // p8 in phase1; p = g + 8*ii in phase2
  float t8x[8], t8y[8];              // tw[8 g k2]
#pragma unroll
  for (int k2 = 0; k2 < 8; ++k2) {
    const float2 w = tw[(8 * g * k2) & 63];
    t8x[k2] = w.x; t8y[k2] = w.y;
  }
#pragma unroll
  for (int k1 = 0; k1 < 8; ++k1) {
    float accr = 0.f, acci = 0.f;
#pragma unroll
    for (int k2 = 0; k2 < 8; ++k2) {
      const float Hr = Hre[k1 + 8 * k2][d];
      const float Hi = Him[k1 + 8 * k2][d];
      accr += Hr * t8x[k2] - Hi * t8y[k2];
      acci += Hr * t8y[k2] + Hi * t8x[k2];
    }
    Bre[k1 * 8 + g][d] = accr;
    Bim[k1 * 8 + g][d] = acci;
  }
  __syncthreads();
  float Br[8], Bi[8];                // reg-cache: same B row set for all ii
#pragma unroll
  for (int k1 = 0; k1 < 8; ++k1) {
    Br[k1] = Bre[k1 * 8 + g][d];
    Bi[k1] = Bim[k1 * 8 + g][d];
  }
#pragma unroll
  for (int ii = 0; ii < 8; ++ii) {
    const int p = g + 8 * ii;
    float accr = 0.f, acci = 0.f;
#pragma unroll
    for (int k1 = 0; k1 < 8; ++k1) {
      const float2 w = tw[(p * k1) & 63];
      accr += Br[k1] * w.x - Bi[k1] * w.y;
      if (!REAL_ONLY) acci += Br[k1] * w.y + Bi[k1] * w.x;
    }
    const size_t off = (((size_t)(b * 64 + j) * 64 + p) * 2 + s) * 64 + dh * 32 + d;
    if (REAL_ONLY) {
      out[off] = accr;
    } else {
      ((float2*)out)[off] = make_float2(accr, acci);
    }
  }
}

extern "C" void kernel_launch(void* const* d_in, const int* in_sizes, int n_in,
                              void* d_out, int out_size, void* d_ws, size_t ws_size,
                              hipStream_t stream)
{
  const float* fre     = (const float*)d_in[0];
  const float* fim     = (const float*)d_in[1];
  const float* kre     = (const float*)d_in[2];
  const float* kim     = (const float*)d_in[3];
  const float* leg_in  = (const float*)d_in[4];
  const float* leg_out = (const float*)d_in[5];
  const float* qw      = (const float*)d_in[6];
  float* out = (float*)d_out;

  const size_t NG = 16515072;   // 63*2*64*32*64
  const size_t NA = 8257536;    // 32*63*32*128
  float* ws = (float*)d_ws;
  float* gre = ws;              // ws region: g, later h (aliased; g dead)
  float* gim = gre + NG;
  float* hre = gre;
  float* him = gim;
  float* are = out;             // a lives in d_out; dead before k_idft
  float* aim = are + NA;        // overwrites every element of d_out

  k_dft_fwd<<<8192, 256, 0, stream>>>(fre, fim, qw, gre, gim);
  k_leg_fwd<<<1008, 256, 0, stream>>>(leg_in, gre, gim, are, aim);
  k_mix<<<1024, 256, 0, stream>>>(are, aim, kre, kim);
  k_leg_bwd<<<1008, 256, 0, stream>>>(leg_out, are, aim, hre, him);
  if (out_size >= 33554432) {
    k_idft<0><<<8192, 256, 0, stream>>>(hre, him, out);
  } else {
    k_idft<1><<<8192, 256, 0, stream>>>(hre, him, out);
  }
}

// Round 10
// 394.937 us; speedup vs baseline: 1.0637x; 1.0637x over previous
//
#include <hip/hip_runtime.h>

// Spin-weighted spherical convolution, R=64, L=32, M=63, S=2, C=64, B=32.
// Stages: DFT(phi) -> Legendre fwd -> channel mix (in-place) -> Legendre bwd
// -> IDFT(phi). All fp32 (no fp32 MFMA on CDNA4).
// R3: k_leg_bwd spill fix (2968 -> 678 us, confirmed).
// R6: radix-8x8 DFT/IDFT (678 -> 407 us, confirmed).
// R7/R9: k_mix prefetch attempt REGRESSED (88 -> 103 us, VALU 57% flat) ->
// latency theory falsified. Real cost: 8 scalar ds_read_b32 per ic + issue
// overhead. R9 fix: ic in groups of 4, a-reads as ds_read_b128 (4x fewer
// LDS issues), k float4s per group, 256-FMA unrolled body, no manual
// prefetch. Pad dropped (column reads are broadcasts). launch_bounds(256,4).

#define TWO_PI_F 6.283185307179586f

// g layout: [mi(63)][s(2)][j(64)][b(32)][c(64)]  -> 16,515,072 floats per re/im
// a layout: [l(32)][mi(63)][b(32)][ic(128)]      -> 8,257,536 floats per re/im
// h layout: [b(32)][j(64)][mi(63)][sd(128)]      -> 16,515,072 floats per re/im

// Radix-8x8 forward DFT. Block = (b, j, s, ch): 32 channels x 8 k8-groups.
__global__ __launch_bounds__(256) void k_dft_fwd(
    const float* __restrict__ fre, const float* __restrict__ fim,
    const float* __restrict__ qw, float* __restrict__ gre, float* __restrict__ gim)
{
  __shared__ float sre[64][32];
  __shared__ float sim2[64][32];
  __shared__ float Are[64][32];
  __shared__ float Aim[64][32];
  __shared__ float2 tw[64];
  const int bid = blockIdx.x;          // (((b*64 + j)*2 + s)*2 + ch)
  const int ch = bid & 1;
  const int s = (bid >> 1) & 1;
  const int j = (bid >> 2) & 63;
  const int b = bid >> 8;
  const int t = threadIdx.x;
  if (t < 64) {
    float ang = (TWO_PI_F / 64.0f) * (float)t;
    tw[t] = make_float2(cosf(ang), sinf(ang));
  }
  const int coff = s * 64 + ch * 32;
  const size_t base = ((size_t)(b * 64 + j) * 64) * 128 + coff;
  for (int v = t; v < 512; v += 256) {
    const int p = v >> 3;
    const int q4 = (v & 7) * 4;
    *(float4*)(&sre[p][q4])  = *(const float4*)(fre + base + (size_t)p * 128 + q4);
    *(float4*)(&sim2[p][q4]) = *(const float4*)(fim + base + (size_t)p * 128 + q4);
  }
  __syncthreads();
  const int c = t & 31;
  const int g = t >> 5;                // k8 in phase1; k = g + 8*ii in phase2
  float t8x[8], t8y[8];                // W8^{-g p2} = conj(tw[8 g p2])
#pragma unroll
  for (int p2 = 0; p2 < 8; ++p2) {
    const float2 w = tw[(8 * g * p2) & 63];
    t8x[p2] = w.x; t8y[p2] = w.y;
  }
#pragma unroll
  for (int p1 = 0; p1 < 8; ++p1) {
    float accr = 0.f, acci = 0.f;
#pragma unroll
    for (int p2 = 0; p2 < 8; ++p2) {
      const float fr = sre[p1 + 8 * p2][c];
      const float fi = sim2[p1 + 8 * p2][c];
      accr += fr * t8x[p2] + fi * t8y[p2];
      acci += fi * t8x[p2] - fr * t8y[p2];
    }
    Are[p1 * 8 + g][c] = accr;
    Aim[p1 * 8 + g][c] = acci;
  }
  __syncthreads();
  const float scale = (TWO_PI_F / 64.0f) * qw[j];
  float Ar[8], Ai[8];                  // reg-cache: same A row set for all ii
#pragma unroll
  for (int p1 = 0; p1 < 8; ++p1) {
    Ar[p1] = Are[p1 * 8 + g][c];
    Ai[p1] = Aim[p1 * 8 + g][c];
  }
#pragma unroll
  for (int ii = 0; ii < 8; ++ii) {
    const int k = g + 8 * ii;
    if (k == 32) continue;             // |m|>31 unused (wave-uniform branch)
    float accr = 0.f, acci = 0.f;
#pragma unroll
    for (int p1 = 0; p1 < 8; ++p1) {
      const float2 w = tw[(k * p1) & 63];
      accr += Ar[p1] * w.x + Ai[p1] * w.y;
      acci += Ai[p1] * w.x - Ar[p1] * w.y;
    }
    const int mi = (k < 32) ? (k + 31) : (k - 33);   // m = k or k-64; mi = m+31
    const size_t off = ((size_t)(mi * 2 + s) * 64 + j) * 2048 + b * 64 + ch * 32 + c;
    gre[off] = accr * scale;
    gim[off] = acci * scale;
  }
}

__global__ __launch_bounds__(256) void k_leg_fwd(
    const float* __restrict__ leg, const float* __restrict__ gre,
    const float* __restrict__ gim, float* __restrict__ are, float* __restrict__ aim)
{
  __shared__ float legS[32][64];
  const int bid = blockIdx.x;          // (mi*2 + s)*8 + tile
  const int tile = bid & 7;
  const int s = (bid >> 3) & 1;
  const int mi = bid >> 4;             // 0..62
  const int mval = mi - 31;
  const int am = mval < 0 ? -mval : mval;
  const int nl = 32 - am;
  const int t = threadIdx.x;
  for (int v = t; v < 2048; v += 256) {
    const int l2 = v >> 6, jj = v & 63;
    float val = 0.f;
    if (l2 < nl) {
      const int l = am + l2;
      val = leg[(size_t)((s * 32 + l) * 63 + mi) * 64 + jj];
    }
    legS[l2][jj] = val;
  }
  __syncthreads();
  const int bc = tile * 256 + t;
  const size_t gbase = (size_t)(mi * 2 + s) * 131072 + bc;
  float xr[32], xi[32];
#pragma unroll
  for (int l2 = 0; l2 < 32; ++l2) { xr[l2] = 0.f; xi[l2] = 0.f; }
  for (int j4 = 0; j4 < 16; ++j4) {
    float gr[4], gi[4];
#pragma unroll
    for (int u = 0; u < 4; ++u) {
      gr[u] = gre[gbase + (size_t)(j4 * 4 + u) * 2048];
      gi[u] = gim[gbase + (size_t)(j4 * 4 + u) * 2048];
    }
#pragma unroll
    for (int l2 = 0; l2 < 32; ++l2) {
      const float4 lg = *(const float4*)(&legS[l2][j4 * 4]);
      xr[l2] += lg.x * gr[0] + lg.y * gr[1] + lg.z * gr[2] + lg.w * gr[3];
      xi[l2] += lg.x * gi[0] + lg.y * gi[1] + lg.z * gi[2] + lg.w * gi[3];
    }
  }
  const int b = bc >> 6, c = bc & 63;
#pragma unroll
  for (int l2 = 0; l2 < 32; ++l2) {
    if (l2 < nl) {
      const int l = am + l2;
      const size_t off = ((size_t)(l * 63 + mi) * 32 + b) * 128 + s * 64 + c;
      are[off] = xr[l2];
      aim[off] = xi[l2];
    }
  }
}

// In-place channel/spin mix, R9: ic processed in groups of 4 with
// ds_read_b128 a-loads and fully unrolled 256-FMA body.
#define F4C(v, u) ((u) == 0 ? (v).x : (u) == 1 ? (v).y : (u) == 2 ? (v).z : (v).w)
__global__ __launch_bounds__(256, 4) void k_mix(
    float* __restrict__ are, float* __restrict__ aim,
    const float* __restrict__ kre, const float* __restrict__ kim)
{
  __shared__ float sar[32][128];
  __shared__ float sai[32][128];
  const int q = blockIdx.x;        // 1024 valid (l,mi): q = l^2 + (mi - (31-l))
  int l = (int)floorf(sqrtf((float)q));
  if ((l + 1) * (l + 1) <= q) ++l;
  if (l * l > q) --l;
  const int mi = 31 - l + (q - l * l);
  const int t = threadIdx.x;
  const size_t abase = (size_t)(l * 63 + mi) * 4096;
  for (int v = t; v < 1024; v += 256) {
    *(float4*)(&sar[0][0] + (size_t)v * 4) = *(const float4*)(are + abase + v * 4);
    *(float4*)(&sai[0][0] + (size_t)v * 4) = *(const float4*)(aim + abase + v * 4);
  }
  __syncthreads();
  const int od0 = (t & 31) * 4;
  const int b0 = (t >> 5) * 4;
  const int o = od0 >> 6;
  const int d0 = od0 & 63;
  // k element for (ic = i*64+cc, od = o*64+dd): kre[l][i][o][cc][dd]
  const float* __restrict__ kr_p = kre + (size_t)l * 16384 + (size_t)o * 4096 + d0;
  const float* __restrict__ ki_p = kim + (size_t)l * 16384 + (size_t)o * 4096 + d0;
  float cr[4][4], ci[4][4];
#pragma unroll
  for (int r = 0; r < 4; ++r)
#pragma unroll
    for (int u = 0; u < 4; ++u) { cr[r][u] = 0.f; ci[r][u] = 0.f; }
#pragma unroll 1
  for (int ic4 = 0; ic4 < 32; ++ic4) {
    const int ic0 = ic4 * 4;
    const int i = ic0 >> 6;                    // constant within group of 4
    const int cc0 = ic0 & 63;
    const float* kb_r = kr_p + (size_t)i * 8192 + (size_t)cc0 * 64;
    const float* kb_i = ki_p + (size_t)i * 8192 + (size_t)cc0 * 64;
    float4 kr4[4], ki4[4];
#pragma unroll
    for (int u = 0; u < 4; ++u) {
      kr4[u] = *(const float4*)(kb_r + (size_t)u * 64);
      ki4[u] = *(const float4*)(kb_i + (size_t)u * 64);
    }
    float4 a4r[4], a4i[4];
#pragma unroll
    for (int r = 0; r < 4; ++r) {
      a4r[r] = *(const float4*)(&sar[b0 + r][ic0]);   // ds_read_b128, broadcast
      a4i[r] = *(const float4*)(&sai[b0 + r][ic0]);
    }
#pragma unroll
    for (int u = 0; u < 4; ++u) {
#pragma unroll
      for (int r = 0; r < 4; ++r) {
        const float arv = F4C(a4r[r], u);
        const float aiv = F4C(a4i[r], u);
        cr[r][0] += arv * kr4[u].x - aiv * ki4[u].x; ci[r][0] += arv * ki4[u].x + aiv * kr4[u].x;
        cr[r][1] += arv * kr4[u].y - aiv * ki4[u].y; ci[r][1] += arv * ki4[u].y + aiv * kr4[u].y;
        cr[r][2] += arv * kr4[u].z - aiv * ki4[u].z; ci[r][2] += arv * ki4[u].z + aiv * kr4[u].z;
        cr[r][3] += arv * kr4[u].w - aiv * ki4[u].w; ci[r][3] += arv * ki4[u].w + aiv * kr4[u].w;
      }
    }
  }
#pragma unroll
  for (int r = 0; r < 4; ++r) {
    const size_t off = abase + (size_t)(b0 + r) * 128 + od0;
    *(float4*)(are + off) = make_float4(cr[r][0], cr[r][1], cr[r][2], cr[r][3]);
    *(float4*)(aim + off) = make_float4(ci[r][0], ci[r][1], ci[r][2], ci[r][3]);
  }
}

// R3 structure: inverted loop nest, j-accumulators in regs (statically
// indexed), x streamed one elem at a time, re/im passes pinned sequential.
__global__ __launch_bounds__(256) void k_leg_bwd(
    const float* __restrict__ leg, const float* __restrict__ ore,
    const float* __restrict__ oim, float* __restrict__ hre, float* __restrict__ him)
{
  __shared__ float legS[32][64];
  const int bid = blockIdx.x;        // (mi*2 + s)*8 + tile
  const int tile = bid & 7;
  const int s = (bid >> 3) & 1;      // output spin
  const int mi = bid >> 4;
  const int mval = mi - 31;
  const int am = mval < 0 ? -mval : mval;
  const int nl = 32 - am;
  const int t = threadIdx.x;
  for (int v = t; v < 2048; v += 256) {
    const int l2 = v >> 6, jj = v & 63;
    float val = 0.f;
    if (l2 < nl) {
      const int l = am + l2;
      val = leg[(size_t)((s * 32 + l) * 63 + mi) * 64 + jj];
    }
    legS[l2][jj] = val;
  }
  __syncthreads();
  const int bd = tile * 256 + t;
  const int b = bd >> 6, d = bd & 63;
  const size_t lstr = (size_t)63 * 32 * 128;                       // a l-stride
  const size_t abase = ((size_t)(am * 63 + mi) * 32 + b) * 128 + s * 64 + d;
  const size_t hb = (size_t)(b * 64) * 8064 + (size_t)mi * 128 + s * 64 + d;
#pragma unroll 1
  for (int pass = 0; pass < 2; ++pass) {
    const float* __restrict__ src = pass ? oim : ore;
    float* __restrict__ dst = pass ? him : hre;
    float acc[16][4];
#pragma unroll
    for (int j4 = 0; j4 < 16; ++j4)
#pragma unroll
      for (int u = 0; u < 4; ++u) acc[j4][u] = 0.f;
#pragma unroll 1
    for (int l2 = 0; l2 < 32; ++l2) {
      if (l2 >= nl) break;
      const float xv = src[abase + (size_t)l2 * lstr];
#pragma unroll
      for (int j4 = 0; j4 < 16; ++j4) {
        const float4 lg = *(const float4*)(&legS[l2][j4 * 4]);
        acc[j4][0] += lg.x * xv;
        acc[j4][1] += lg.y * xv;
        acc[j4][2] += lg.z * xv;
        acc[j4][3] += lg.w * xv;
      }
    }
#pragma unroll
    for (int j4 = 0; j4 < 16; ++j4) {
      const size_t o0 = hb + (size_t)(j4 * 4) * 8064;
      dst[o0]            = acc[j4][0];
      dst[o0 + 8064]     = acc[j4][1];
      dst[o0 + 2 * 8064] = acc[j4][2];
      dst[o0 + 3 * 8064] = acc[j4][3];
    }
  }
}

// Radix-8x8 inverse DFT. Block = (b, j, s, dh): 32 d-channels x 8 p8-groups.
template <int REAL_ONLY>
__global__ __launch_bounds__(256) void k_idft(
    const float* __restrict__ hre, const float* __restrict__ him,
    float* __restrict__ out)
{
  __shared__ float Hre[64][32];
  __shared__ float Him[64][32];
  __shared__ float Bre[64][32];
  __shared__ float Bim[64][32];
  __shared__ float2 tw[64];
  const int bid = blockIdx.x;        // (((b*64 + j)*2 + s)*2 + dh)
  const int dh = bid & 1;
  const int s = (bid >> 1) & 1;
  const int j = (bid >> 2) & 63;
  const int b = bid >> 8;
  const int t = threadIdx.x;
  if (t < 64) {
    float ang = (TWO_PI_F / 64.0f) * (float)t;
    tw[t] = make_float2(cosf(ang), sinf(ang));
  }
  const size_t hbase = (size_t)(b * 64 + j) * 8064 + s * 64 + dh * 32;
  for (int v = t; v < 512; v += 256) {
    const int k = v >> 3;
    const int q4 = (v & 7) * 4;
    float4 vr = make_float4(0.f, 0.f, 0.f, 0.f), vi = vr;
    if (k != 32) {
      const int mi = (k + 31) & 63;
      vr = *(const float4*)(hre + hbase + (size_t)mi * 128 + q4);
      vi = *(const float4*)(him + hbase + (size_t)mi * 128 + q4);
    }
    *(float4*)(&Hre[k][q4]) = vr;
    *(float4*)(&Him[k][q4]) = vi;
  }
  __syncthreads();
  const int d = t & 31;
  const int g = t >> 5;              // p8 in phase1; p = g + 8*ii in phase2
  float t8x[8], t8y[8];              // tw[8 g k2]
#pragma unroll
  for (int k2 = 0; k2 < 8; ++k2) {
    const float2 w = tw[(8 * g * k2) & 63];
    t8x[k2] = w.x; t8y[k2] = w.y;
  }
#pragma unroll
  for (int k1 = 0; k1 < 8; ++k1) {
    float accr = 0.f, acci = 0.f;
#pragma unroll
    for (int k2 = 0; k2 < 8; ++k2) {
      const float Hr = Hre[k1 + 8 * k2][d];
      const float Hi = Him[k1 + 8 * k2][d];
      accr += Hr * t8x[k2] - Hi * t8y[k2];
      acci += Hr * t8y[k2] + Hi * t8x[k2];
    }
    Bre[k1 * 8 + g][d] = accr;
    Bim[k1 * 8 + g][d] = acci;
  }
  __syncthreads();
  float Br[8], Bi[8];                // reg-cache: same B row set for all ii
#pragma unroll
  for (int k1 = 0; k1 < 8; ++k1) {
    Br[k1] = Bre[k1 * 8 + g][d];
    Bi[k1] = Bim[k1 * 8 + g][d];
  }
#pragma unroll
  for (int ii = 0; ii < 8; ++ii) {
    const int p = g + 8 * ii;
    float accr = 0.f, acci = 0.f;
#pragma unroll
    for (int k1 = 0; k1 < 8; ++k1) {
      const float2 w = tw[(p * k1) & 63];
      accr += Br[k1] * w.x - Bi[k1] * w.y;
      if (!REAL_ONLY) acci += Br[k1] * w.y + Bi[k1] * w.x;
    }
    const size_t off = (((size_t)(b * 64 + j) * 64 + p) * 2 + s) * 64 + dh * 32 + d;
    if (REAL_ONLY) {
      out[off] = accr;
    } else {
      ((float2*)out)[off] = make_float2(accr, acci);
    }
  }
}

extern "C" void kernel_launch(void* const* d_in, const int* in_sizes, int n_in,
                              void* d_out, int out_size, void* d_ws, size_t ws_size,
                              hipStream_t stream)
{
  const float* fre     = (const float*)d_in[0];
  const float* fim     = (const float*)d_in[1];
  const float* kre     = (const float*)d_in[2];
  const float* kim     = (const float*)d_in[3];
  const float* leg_in  = (const float*)d_in[4];
  const float* leg_out = (const float*)d_in[5];
  const float* qw      = (const float*)d_in[6];
  float* out = (float*)d_out;

  const size_t NG = 16515072;   // 63*2*64*32*64
  const size_t NA = 8257536;    // 32*63*32*128
  float* ws = (float*)d_ws;
  float* gre = ws;              // ws region: g, later h (aliased; g dead)
  float* gim = gre + NG;
  float* hre = gre;
  float* him = gim;
  float* are = out;             // a lives in d_out; dead before k_idft
  float* aim = are + NA;        // overwrites every element of d_out

  k_dft_fwd<<<8192, 256, 0, stream>>>(fre, fim, qw, gre, gim);
  k_leg_fwd<<<1008, 256, 0, stream>>>(leg_in, gre, gim, are, aim);
  k_mix<<<1024, 256, 0, stream>>>(are, aim, kre, kim);
  k_leg_bwd<<<1008, 256, 0, stream>>>(leg_out, are, aim, hre, him);
  if (out_size >= 33554432) {
    k_idft<0><<<8192, 256, 0, stream>>>(hre, him, out);
  } else {
    k_idft<1><<<8192, 256, 0, stream>>>(hre, him, out);
  }
}